// Round 1
// baseline (3445.404 us; speedup 1.0000x reference)
//
#include <hip/hip_runtime.h>
#include <hip/hip_bf16.h>

#define N_CELLS 20000
#define N_GENES 3000
#define HID 512
#define OUT 128
#define E_CELL 320000
#define E_GENE 48000

#define ACT_NONE 0
#define ACT_RELU 1
#define ACT_LEAKY 2

__device__ __forceinline__ float apply_act(float v, int act) {
  if (act == 1) return fmaxf(v, 0.0f);
  if (act == 2) return v >= 0.0f ? v : 0.01f * v;
  return v;
}

// ---------------- fp32 tiled GEMM: C[M,N] = A[M,K] @ B[K,N] (+bias, act) -----
// 128x128 tile, BK=8, 256 threads, 8x8 per thread. Requires N % 128 == 0,
// K % 8 == 0, K % 4 == 0 (float4 loads). M guarded.
__launch_bounds__(256, 2)
__global__ void gemm128(const float* __restrict__ A, const float* __restrict__ B,
                        const float* __restrict__ bias, float* __restrict__ C,
                        int M, int N, int K, int act) {
  __shared__ float As[8][128];
  __shared__ float Bs[8][128];
  const int tid = threadIdx.x;
  const int brow = blockIdx.y * 128;
  const int bcol = blockIdx.x * 128;
  const int tx = tid & 15;
  const int ty = tid >> 4;
  const int ar = tid >> 1;          // 0..127 (A tile row)
  const int ak = (tid & 1) << 2;    // 0 or 4 (A tile k)
  const int bk = tid >> 5;          // 0..7   (B tile k)
  const int bc = (tid & 31) << 2;   // 0..124 (B tile col)
  const int arow = brow + ar;
  const bool a_ok = (arow < M);
  const long a_base = (long)arow * K + ak;
  const long b_base = (long)bk * N + bcol + bc;

  float acc[8][8];
#pragma unroll
  for (int i = 0; i < 8; ++i)
#pragma unroll
    for (int j = 0; j < 8; ++j) acc[i][j] = 0.0f;

  for (int k0 = 0; k0 < K; k0 += 8) {
    float4 av;
    if (a_ok) av = *(const float4*)(A + a_base + k0);
    else av = make_float4(0.f, 0.f, 0.f, 0.f);
    float4 bv = *(const float4*)(B + b_base + (long)k0 * N);
    As[ak + 0][ar] = av.x;
    As[ak + 1][ar] = av.y;
    As[ak + 2][ar] = av.z;
    As[ak + 3][ar] = av.w;
    *(float4*)&Bs[bk][bc] = bv;
    __syncthreads();
#pragma unroll
    for (int kk = 0; kk < 8; ++kk) {
      float a[8], b[8];
      *(float4*)(a)     = *(const float4*)&As[kk][ty * 8];
      *(float4*)(a + 4) = *(const float4*)&As[kk][ty * 8 + 4];
      *(float4*)(b)     = *(const float4*)&Bs[kk][tx * 8];
      *(float4*)(b + 4) = *(const float4*)&Bs[kk][tx * 8 + 4];
#pragma unroll
      for (int i = 0; i < 8; ++i)
#pragma unroll
        for (int j = 0; j < 8; ++j)
          acc[i][j] = fmaf(a[i], b[j], acc[i][j]);
    }
    __syncthreads();
  }

#pragma unroll
  for (int i = 0; i < 8; ++i) {
    int grow = brow + ty * 8 + i;
    if (grow >= M) break;
    float outv[8];
#pragma unroll
    for (int j = 0; j < 8; ++j) {
      float v = acc[i][j];
      if (bias) v += bias[bcol + tx * 8 + j];
      outv[j] = apply_act(v, act);
    }
    *(float4*)(C + (long)grow * N + bcol + tx * 8)     = *(float4*)(outv);
    *(float4*)(C + (long)grow * N + bcol + tx * 8 + 4) = *(float4*)(outv + 4);
  }
}

// ------------- TN split-K GEMM: part[split] = A[krange,:]^T @ B[krange,:] ----
// A: [K,M] row-major, B: [K,N] row-major, N == 128. M % 4 == 0, kchunk % 8 == 0.
__launch_bounds__(256, 2)
__global__ void gemm_tn_splitk(const float* __restrict__ A, const float* __restrict__ B,
                               float* __restrict__ part,
                               int M, int N, int kchunk) {
  __shared__ float As[8][128];
  __shared__ float Bs[8][128];
  const int tid = threadIdx.x;
  const int bm = blockIdx.x * 128;
  const int split = blockIdx.y;
  const int k_begin = split * kchunk;
  const int k_end = k_begin + kchunk;
  const int tx = tid & 15;
  const int ty = tid >> 4;
  const int kr = tid >> 5;          // 0..7
  const int c4 = (tid & 31) << 2;   // 0..124
  const int gm = bm + c4;
  const bool a_ok = (gm < M);

  float acc[8][8];
#pragma unroll
  for (int i = 0; i < 8; ++i)
#pragma unroll
    for (int j = 0; j < 8; ++j) acc[i][j] = 0.0f;

  for (int k0 = k_begin; k0 < k_end; k0 += 8) {
    float4 av;
    if (a_ok) av = *(const float4*)(A + (long)(k0 + kr) * M + gm);
    else av = make_float4(0.f, 0.f, 0.f, 0.f);
    float4 bv = *(const float4*)(B + (long)(k0 + kr) * N + c4);
    *(float4*)&As[kr][c4] = av;
    *(float4*)&Bs[kr][c4] = bv;
    __syncthreads();
#pragma unroll
    for (int kk = 0; kk < 8; ++kk) {
      float a[8], b[8];
      *(float4*)(a)     = *(const float4*)&As[kk][ty * 8];
      *(float4*)(a + 4) = *(const float4*)&As[kk][ty * 8 + 4];
      *(float4*)(b)     = *(const float4*)&Bs[kk][tx * 8];
      *(float4*)(b + 4) = *(const float4*)&Bs[kk][tx * 8 + 4];
#pragma unroll
      for (int i = 0; i < 8; ++i)
#pragma unroll
        for (int j = 0; j < 8; ++j)
          acc[i][j] = fmaf(a[i], b[j], acc[i][j]);
    }
    __syncthreads();
  }

  float* cp = part + (long)split * M * N;
#pragma unroll
  for (int i = 0; i < 8; ++i) {
    int m = bm + ty * 8 + i;
    if (m >= M) break;
    *(float4*)(cp + (long)m * N + tx * 8)     = *(float4*)(acc[i]);
    *(float4*)(cp + (long)m * N + tx * 8 + 4) = *(float4*)(acc[i] + 4);
  }
}

// ----------------------------- CSR build ------------------------------------
__global__ void hist_kernel(const int* __restrict__ dst, int* __restrict__ cnt, int E) {
  for (int e = blockIdx.x * blockDim.x + threadIdx.x; e < E; e += gridDim.x * blockDim.x)
    atomicAdd(&cnt[dst[e]], 1);
}

__launch_bounds__(1024)
__global__ void scan_build(const int* __restrict__ cnt, int* __restrict__ row_ptr,
                           float* __restrict__ dinv, int n) {
  __shared__ int part[1024];
  const int tid = threadIdx.x;
  const int per = (n + 1023) >> 10;
  const int start = tid * per;
  const int end = min(start + per, n);
  int s = 0;
  for (int i = start; i < end; ++i) s += cnt[i];
  part[tid] = s;
  __syncthreads();
  for (int off = 1; off < 1024; off <<= 1) {
    int v = (tid >= off) ? part[tid - off] : 0;
    __syncthreads();
    part[tid] += v;
    __syncthreads();
  }
  int run = (tid > 0) ? part[tid - 1] : 0;
  for (int i = start; i < end; ++i) {
    row_ptr[i] = run;
    int c = cnt[i];
    dinv[i] = rsqrtf((float)(c + 1));  // deg = in-edges + self-loop, >= 1
    run += c;
  }
  if (tid == 1023) row_ptr[n] = part[1023];
}

__global__ void scatter_kernel(const int* __restrict__ src, const int* __restrict__ dst,
                               const int* __restrict__ rp, int* __restrict__ fill,
                               int* __restrict__ col, int E) {
  for (int e = blockIdx.x * blockDim.x + threadIdx.x; e < E; e += gridDim.x * blockDim.x) {
    int d = dst[e];
    int p = atomicAdd(&fill[d], 1);
    col[rp[d] + p] = src[e];
  }
}

// ------------------- GCN aggregation (gather, CSR by dst) -------------------
// out[i] = act( sum_{e:(s->i)} h[s]*dinv[s]*dinv[i] + h[i]*dinv[i]^2 + bias )
__launch_bounds__(256)
__global__ void gcn_agg(const float* __restrict__ h, const int* __restrict__ row_ptr,
                        const int* __restrict__ col, const float* __restrict__ dinv,
                        const float* __restrict__ bias, float* __restrict__ out,
                        int n, int F, int act) {
  const int tpn = F >> 2;                 // threads per node
  const int npb = blockDim.x / tpn;       // nodes per block
  const int node = blockIdx.x * npb + threadIdx.x / tpn;
  const int j = (threadIdx.x % tpn) << 2;
  if (node >= n) return;
  const float di = dinv[node];
  const float4 hv0 = *(const float4*)(h + (long)node * F + j);
  const float w0 = di * di;
  float ax = hv0.x * w0, ay = hv0.y * w0, az = hv0.z * w0, aw = hv0.w * w0;
  const int e0 = row_ptr[node], e1 = row_ptr[node + 1];
  for (int e = e0; e < e1; ++e) {
    const int s = col[e];
    const float w = dinv[s] * di;
    const float4 hv = *(const float4*)(h + (long)s * F + j);
    ax = fmaf(hv.x, w, ax);
    ay = fmaf(hv.y, w, ay);
    az = fmaf(hv.z, w, az);
    aw = fmaf(hv.w, w, aw);
  }
  const float4 bv = *(const float4*)(bias + j);
  float4 o;
  o.x = apply_act(ax + bv.x, act);
  o.y = apply_act(ay + bv.y, act);
  o.z = apply_act(az + bv.z, act);
  o.w = apply_act(aw + bv.w, act);
  *(float4*)(out + (long)node * F + j) = o;
}

// ----------------------------- misc small kernels ---------------------------
__global__ void reduce_part(const float* __restrict__ part, float* __restrict__ xt,
                            int n, int nsplit) {
  const int i = blockIdx.x * blockDim.x + threadIdx.x;
  if (i >= n) return;
  float s = 0.f;
  for (int sp = 0; sp < nsplit; ++sp) s += part[(long)sp * n + i];
  xt[i] = s;
}

// M1b[0:512][:] = Wp @ xg ; M1b[512][:] = bp @ xg
__launch_bounds__(256)
__global__ void m1_kernel(const float* __restrict__ Wp, const float* __restrict__ bp,
                          const float* __restrict__ xg, float* __restrict__ M1b) {
  const int gid = blockIdx.x * blockDim.x + threadIdx.x;
  if (gid >= 513 * 128) return;
  const int m = gid >> 7, nn = gid & 127;
  const float* a = (m < 512) ? (Wp + (long)m * 3000) : bp;
  float acc = 0.f;
  for (int k = 0; k < 3000; k += 4) {
    acc = fmaf(a[k],     xg[(k)     * 128 + nn], acc);
    acc = fmaf(a[k + 1], xg[(k + 1) * 128 + nn], acc);
    acc = fmaf(a[k + 2], xg[(k + 2) * 128 + nn], acc);
    acc = fmaf(a[k + 3], xg[(k + 3) * 128 + nn], acc);
  }
  M1b[gid] = acc;
}

__launch_bounds__(256)
__global__ void l2norm_rows(const float* __restrict__ in, float* __restrict__ out, int F) {
  const int row = blockIdx.x;
  const float* r = in + (long)row * F;
  float s = 0.0f;
  for (int i = threadIdx.x * 4; i < F; i += blockDim.x * 4) {
    float4 v = *(const float4*)(r + i);
    s = fmaf(v.x, v.x, fmaf(v.y, v.y, fmaf(v.z, v.z, fmaf(v.w, v.w, s))));
  }
#pragma unroll
  for (int off = 32; off > 0; off >>= 1) s += __shfl_down(s, off);
  __shared__ float wsum[4];
  __shared__ float scale_s;
  const int wid = threadIdx.x >> 6;
  const int lane = threadIdx.x & 63;
  if (lane == 0) wsum[wid] = s;
  __syncthreads();
  if (threadIdx.x == 0) {
    float t = wsum[0] + wsum[1] + wsum[2] + wsum[3];
    scale_s = 1.0f / fmaxf(sqrtf(t), 1e-12f);
  }
  __syncthreads();
  const float sc = scale_s;
  float* o = out + (long)row * F;
  for (int i = threadIdx.x * 4; i < F; i += blockDim.x * 4) {
    float4 v = *(const float4*)(r + i);
    v.x *= sc; v.y *= sc; v.z *= sc; v.w *= sc;
    *(float4*)(o + i) = v;
  }
}

// ---------------------------------------------------------------------------
extern "C" void kernel_launch(void* const* d_in, const int* in_sizes, int n_in,
                              void* d_out, int out_size, void* d_ws, size_t ws_size,
                              hipStream_t stream) {
  const float* x0 = (const float*)d_in[0];
  const float* x1 = (const float*)d_in[1];
  const int*   ei  = (const int*)d_in[2];
  const int*   eig = (const int*)d_in[3];
  const float* Wm = (const float*)d_in[4];
  const float* bm = (const float*)d_in[5];
  const float* W1 = (const float*)d_in[6];
  const float* b1 = (const float*)d_in[7];
  const float* W2 = (const float*)d_in[8];
  const float* b2 = (const float*)d_in[9];
  const float* W3 = (const float*)d_in[10];
  const float* b3 = (const float*)d_in[11];
  const float* Wp = (const float*)d_in[12];
  const float* bp = (const float*)d_in[13];
  const float* Wg = (const float*)d_in[14];
  const float* bg = (const float*)d_in[15];

  // ---- workspace layout (floats) ----
  float* ws = (float*)d_ws;
  size_t o = 0;
  float* h1   = ws + o; o += (size_t)N_CELLS * HID;        // relu(x0@Wm+bm)
  float* bufB = ws + o; o += (size_t)N_CELLS * HID;
  float* bufC = ws + o; o += (size_t)N_CELLS * HID;
  float* zpre = ws + o; o += (size_t)N_CELLS * OUT;
  const int NSPLIT = 10;
  float* part = ws + o; o += (size_t)NSPLIT * N_GENES * OUT;
  float* xt   = ws + o; o += (size_t)N_GENES * OUT;
  float* xg   = ws + o; o += (size_t)N_GENES * OUT;
  float* M1b  = ws + o; o += 513 * 128;
  float* dinv_c = ws + o; o += N_CELLS;
  float* dinv_g = ws + o; o += N_GENES + 64;
  int* ip = (int*)(ws + o);
  int* rp_c  = ip; ip += N_CELLS + 64;
  int* rp_g  = ip; ip += N_GENES + 64;
  int* col_c = ip; ip += E_CELL;
  int* col_g = ip; ip += E_GENE;
  int* cnt_c = ip; ip += N_CELLS;   // contiguous zero region starts here
  int* fill_c = ip; ip += N_CELLS;
  int* cnt_g = ip; ip += N_GENES;
  int* fill_g = ip; ip += N_GENES;
  (void)fill_g; (void)ws_size; (void)in_sizes; (void)n_in; (void)out_size;

  const int* src_c = ei;  const int* dst_c = ei + E_CELL;
  const int* src_g = eig; const int* dst_g = eig + E_GENE;

  float* out_emb1 = (float*)d_out;
  float* out_emb2 = out_emb1 + (size_t)N_CELLS * HID;
  float* out_z1   = out_emb2 + (size_t)N_CELLS * HID;
  float* out_z2   = out_z1 + (size_t)N_CELLS * OUT;

  // ---- CSR build for both graphs ----
  hipMemsetAsync(cnt_c, 0, (size_t)(2 * N_CELLS + 2 * N_GENES) * sizeof(int), stream);
  hist_kernel<<<1024, 256, 0, stream>>>(dst_c, cnt_c, E_CELL);
  hist_kernel<<<256, 256, 0, stream>>>(dst_g, cnt_g, E_GENE);
  scan_build<<<1, 1024, 0, stream>>>(cnt_c, rp_c, dinv_c, N_CELLS);
  scan_build<<<1, 1024, 0, stream>>>(cnt_g, rp_g, dinv_g, N_GENES);
  scatter_kernel<<<1024, 256, 0, stream>>>(src_c, dst_c, rp_c, fill_c, col_c, E_CELL);
  scatter_kernel<<<256, 256, 0, stream>>>(src_g, dst_g, rp_g, fill_g, col_g, E_GENE);

  const dim3 g512(HID / 128, (N_CELLS + 127) / 128);   // (4,157)

  // MLP branch: h1 = relu(x0 @ Wm + bm)
  gemm128<<<g512, 256, 0, stream>>>(x0, Wm, bm, h1, N_CELLS, HID, N_GENES, ACT_RELU);

  // GCN branch
  gemm128<<<g512, 256, 0, stream>>>(x1, W1, nullptr, bufB, N_CELLS, HID, N_GENES, ACT_NONE);
  gcn_agg<<<N_CELLS / 2, 256, 0, stream>>>(bufB, rp_c, col_c, dinv_c, b1, bufC, N_CELLS, HID, ACT_LEAKY);
  gemm128<<<g512, 256, 0, stream>>>(bufC, W2, nullptr, bufB, N_CELLS, HID, HID, ACT_NONE);
  gcn_agg<<<N_CELLS / 2, 256, 0, stream>>>(bufB, rp_c, col_c, dinv_c, b2, bufC, N_CELLS, HID, ACT_LEAKY);
  gemm128<<<g512, 256, 0, stream>>>(bufC, W3, b3, bufB, N_CELLS, HID, HID, ACT_LEAKY);  // h2 -> bufB

  // gene branch: xt = x0^T @ Wg (split-K), then gene-graph aggregation
  const dim3 gtn((N_GENES + 127) / 128, NSPLIT);       // (24,10)
  gemm_tn_splitk<<<gtn, 256, 0, stream>>>(x0, Wg, part, N_GENES, OUT, N_CELLS / NSPLIT);
  reduce_part<<<(N_GENES * OUT + 255) / 256, 256, 0, stream>>>(part, xt, N_GENES * OUT, NSPLIT);
  gcn_agg<<<(N_GENES + 7) / 8, 256, 0, stream>>>(xt, rp_g, col_g, dinv_g, bg, xg, N_GENES, OUT, ACT_RELU);

  // M1 = Wp @ xg (and bxg = bp @ xg as row 512)
  m1_kernel<<<(513 * 128 + 255) / 256, 256, 0, stream>>>(Wp, bp, xg, M1b);

  // z1 = l2norm(h1 @ M1 + bxg); z2 = l2norm(h2 @ M1 + bxg)
  const dim3 gz(1, (N_CELLS + 127) / 128);
  gemm128<<<gz, 256, 0, stream>>>(h1, M1b, M1b + 512 * 128, zpre, N_CELLS, OUT, HID, ACT_NONE);
  l2norm_rows<<<N_CELLS, 256, 0, stream>>>(zpre, out_z1, OUT);
  gemm128<<<gz, 256, 0, stream>>>(bufB, M1b, M1b + 512 * 128, zpre, N_CELLS, OUT, HID, ACT_NONE);
  l2norm_rows<<<N_CELLS, 256, 0, stream>>>(zpre, out_z2, OUT);

  // emb_1 / emb_2
  l2norm_rows<<<N_CELLS, 256, 0, stream>>>(h1, out_emb1, HID);
  l2norm_rows<<<N_CELLS, 256, 0, stream>>>(bufB, out_emb2, HID);
}

// Round 2
// 1968.663 us; speedup vs baseline: 1.7501x; 1.7501x over previous
//
#include <hip/hip_runtime.h>
#include <hip/hip_bf16.h>

#define N_CELLS 20000
#define N_GENES 3000
#define HID 512
#define OUT 128
#define E_CELL 320000
#define E_GENE 48000

#define ACT_NONE 0
#define ACT_RELU 1
#define ACT_LEAKY 2

__device__ __forceinline__ float apply_act(float v, int act) {
  if (act == 1) return fmaxf(v, 0.0f);
  if (act == 2) return v >= 0.0f ? v : 0.01f * v;
  return v;
}

typedef __attribute__((ext_vector_type(8))) short bf16x8;
typedef __attribute__((ext_vector_type(4))) float f32x4;

union FragAB { bf16x8 v; unsigned short e[8]; };

__device__ __forceinline__ void gload16(const void* g, const void* lds_base) {
  __builtin_amdgcn_global_load_lds(
      (const __attribute__((address_space(1))) unsigned int*)g,
      (__attribute__((address_space(3))) unsigned int*)lds_base, 16, 0, 0);
}

__device__ __forceinline__ void split_bf(float f, unsigned short& h, unsigned short& l) {
  __hip_bfloat16 hb = __float2bfloat16(f);   // RN
  union { __hip_bfloat16 b; unsigned short u; } c1; c1.b = hb; h = c1.u;
  float rem = f - __bfloat162float(hb);
  __hip_bfloat16 lb = __float2bfloat16(rem);
  union { __hip_bfloat16 b; unsigned short u; } c2; c2.b = lb; l = c2.u;
}

// ============ MFMA split-bf16 GEMM: C[M,N] = A[M,K](fp32) @ W + bias, act ====
// W pre-transposed+split: ushort [N][2*Kpad]: row n = [hi(0..Kpad) | lo(0..Kpad)],
// zeros for k >= K. 128x128 tile, BK=32, 4 waves (2x2 of 64x64), 16x16x32 MFMA.
// LDS XOR-swizzled (chunk ^= row&7) on both stage-source and read side.
__launch_bounds__(256, 2)
__global__ void gemm_mfma(const float* __restrict__ A, const unsigned short* __restrict__ Wc,
                          const float* __restrict__ bias, float* __restrict__ C,
                          int M, int N, int K, int Kpad, int act) {
  __shared__ float As[128 * 32];           // 16 KB, [row][32 floats] (swizzled 16B chunks)
  __shared__ unsigned short Bs[128 * 64];  // 16 KB, [row][hi 32 | lo 32] bf16 (swizzled)
  const int tid = threadIdx.x;
  const int wave = tid >> 6;
  const int lane = tid & 63;
  const int l15 = lane & 15, l4 = lane >> 4;
  const int brow = blockIdx.y * 128, bcol = blockIdx.x * 128;
  const int wm = (wave >> 1) * 64, wn = (wave & 1) * 64;

  f32x4 acc[4][4] = {};

  const int nt = (K + 31) >> 5;
  const int ktail = K & 31;
  const size_t wstride = 2 * (size_t)Kpad;

  for (int t = 0; t < nt; ++t) {
    const int k0 = t << 5;
    const bool tail = (ktail != 0) && (t == nt - 1);

    // ---- stage B tile: 128 rows x (hi32|lo32) bf16 = 16 KB = 4 rounds ----
#pragma unroll
    for (int r = 0; r < 4; ++r) {
      int c = r * 256 + tid;                 // 16B chunk id, 0..1023
      int row = c >> 3, sub = c & 7;
      int un = sub ^ (row & 7);              // logical chunk (inverse swizzle)
      const unsigned short* gb = Wc + (size_t)(bcol + row) * wstride +
                                 (size_t)(un >> 2) * Kpad + k0 + (un & 3) * 8;
      gload16(gb, (const char*)Bs + r * 4096 + wave * 1024);
    }
    // ---- stage A tile: 128 rows x 32 fp32 = 16 KB = 4 rounds ----
    if (!tail) {
#pragma unroll
      for (int r = 0; r < 4; ++r) {
        int c = r * 256 + tid;
        int row = c >> 3, sub = c & 7;
        int lc = sub ^ (row & 7);            // logical 4-float chunk
        int grow = brow + row; if (grow >= M) grow = M - 1;
        const float* ga = A + (size_t)grow * K + k0 + lc * 4;
        gload16(ga, (const char*)As + r * 4096 + wave * 1024);
      }
    } else {
      for (int idx = tid; idx < 4096; idx += 256) {
        int row = idx >> 5, colf = idx & 31;
        int sub = colf >> 2, within = colf & 3;
        int sw = sub ^ (row & 7);
        int grow = brow + row;
        float v = 0.0f;
        if (grow < M && (k0 + colf) < K) v = A[(size_t)grow * K + k0 + colf];
        As[row * 32 + sw * 4 + within] = v;
      }
    }
    __syncthreads();

    // ---- A fragments: read fp32, split to hi/lo bf16 ----
    FragAB ah[4], al[4];
#pragma unroll
    for (int m = 0; m < 4; ++m) {
      int row = wm + m * 16 + l15;
      const f32x4* ap = (const f32x4*)(As + row * 32);
      f32x4 fa0 = ap[(2 * l4) ^ (row & 7)];
      f32x4 fa1 = ap[(2 * l4 + 1) ^ (row & 7)];
      float fv[8] = {fa0.x, fa0.y, fa0.z, fa0.w, fa1.x, fa1.y, fa1.z, fa1.w};
#pragma unroll
      for (int i = 0; i < 8; ++i) split_bf(fv[i], ah[m].e[i], al[m].e[i]);
    }

    // ---- B fragments + MFMA ----
#pragma unroll
    for (int n = 0; n < 4; ++n) {
      int row = wn + n * 16 + l15;
      const bf16x8* bp = (const bf16x8*)(Bs + row * 64);
      bf16x8 bh = bp[l4 ^ (row & 7)];
      bf16x8 bl = bp[(4 + l4) ^ (row & 7)];
#pragma unroll
      for (int m = 0; m < 4; ++m) {
        acc[m][n] = __builtin_amdgcn_mfma_f32_16x16x32_bf16(ah[m].v, bh, acc[m][n], 0, 0, 0);
        acc[m][n] = __builtin_amdgcn_mfma_f32_16x16x32_bf16(al[m].v, bh, acc[m][n], 0, 0, 0);
        acc[m][n] = __builtin_amdgcn_mfma_f32_16x16x32_bf16(ah[m].v, bl, acc[m][n], 0, 0, 0);
      }
    }
    __syncthreads();
  }

  // ---- epilogue: C/D layout col=lane&15, row=(lane>>4)*4+j ----
#pragma unroll
  for (int m = 0; m < 4; ++m) {
    int gr0 = brow + wm + m * 16 + l4 * 4;
#pragma unroll
    for (int n = 0; n < 4; ++n) {
      int gc = bcol + wn + n * 16 + l15;
      float bv = bias ? bias[gc] : 0.0f;
#pragma unroll
      for (int j = 0; j < 4; ++j) {
        int gr = gr0 + j;
        if (gr < M) C[(size_t)gr * N + gc] = apply_act(acc[m][n][j] + bv, act);
      }
    }
  }
}

// ---- weight conversion: W[K,N] fp32 -> WTc ushort [N][hi Kpad | lo Kpad] ----
__global__ void conv_weight(const float* __restrict__ W, unsigned short* __restrict__ WTc,
                            int K, int N, int Kpad) {
  __shared__ float T[32][33];
  const int tx = threadIdx.x & 31, ty = threadIdx.x >> 5;
  const int k0 = blockIdx.y * 32, n0 = blockIdx.x * 32;
#pragma unroll
  for (int r = 0; r < 4; ++r) {
    int k = k0 + ty + r * 8;
    T[ty + r * 8][tx] = (k < K) ? W[(size_t)k * N + n0 + tx] : 0.0f;
  }
  __syncthreads();
#pragma unroll
  for (int r = 0; r < 4; ++r) {
    int n = n0 + ty + r * 8;
    float v = T[tx][ty + r * 8];
    unsigned short h, l;
    split_bf(v, h, l);
    size_t base = (size_t)n * (2 * (size_t)Kpad) + k0 + tx;
    WTc[base] = h;
    WTc[base + Kpad] = l;
  }
}

// ------------- TN split-K GEMM: part[split] = A[krange,:]^T @ B[krange,:] ----
__launch_bounds__(256, 2)
__global__ void gemm_tn_splitk(const float* __restrict__ A, const float* __restrict__ B,
                               float* __restrict__ part,
                               int M, int N, int kchunk) {
  __shared__ float As[8][128];
  __shared__ float Bs[8][128];
  const int tid = threadIdx.x;
  const int bm = blockIdx.x * 128;
  const int split = blockIdx.y;
  const int k_begin = split * kchunk;
  const int k_end = k_begin + kchunk;
  const int tx = tid & 15;
  const int ty = tid >> 4;
  const int kr = tid >> 5;
  const int c4 = (tid & 31) << 2;
  const int gm = bm + c4;
  const bool a_ok = (gm < M);

  float acc[8][8];
#pragma unroll
  for (int i = 0; i < 8; ++i)
#pragma unroll
    for (int j = 0; j < 8; ++j) acc[i][j] = 0.0f;

  for (int k0 = k_begin; k0 < k_end; k0 += 8) {
    float4 av;
    if (a_ok) av = *(const float4*)(A + (long)(k0 + kr) * M + gm);
    else av = make_float4(0.f, 0.f, 0.f, 0.f);
    float4 bv = *(const float4*)(B + (long)(k0 + kr) * N + c4);
    *(float4*)&As[kr][c4] = av;
    *(float4*)&Bs[kr][c4] = bv;
    __syncthreads();
#pragma unroll
    for (int kk = 0; kk < 8; ++kk) {
      float a[8], b[8];
      *(float4*)(a)     = *(const float4*)&As[kk][ty * 8];
      *(float4*)(a + 4) = *(const float4*)&As[kk][ty * 8 + 4];
      *(float4*)(b)     = *(const float4*)&Bs[kk][tx * 8];
      *(float4*)(b + 4) = *(const float4*)&Bs[kk][tx * 8 + 4];
#pragma unroll
      for (int i = 0; i < 8; ++i)
#pragma unroll
        for (int j = 0; j < 8; ++j)
          acc[i][j] = fmaf(a[i], b[j], acc[i][j]);
    }
    __syncthreads();
  }

  float* cp = part + (long)split * M * N;
#pragma unroll
  for (int i = 0; i < 8; ++i) {
    int m = bm + ty * 8 + i;
    if (m >= M) break;
    *(float4*)(cp + (long)m * N + tx * 8)     = *(float4*)(acc[i]);
    *(float4*)(cp + (long)m * N + tx * 8 + 4) = *(float4*)(acc[i] + 4);
  }
}

// ----------------------------- CSR build ------------------------------------
__global__ void hist_kernel(const int* __restrict__ dst, int* __restrict__ cnt, int E) {
  for (int e = blockIdx.x * blockDim.x + threadIdx.x; e < E; e += gridDim.x * blockDim.x)
    atomicAdd(&cnt[dst[e]], 1);
}

__launch_bounds__(1024)
__global__ void scan_build(const int* __restrict__ cnt, int* __restrict__ row_ptr,
                           float* __restrict__ dinv, int n) {
  __shared__ int part[1024];
  const int tid = threadIdx.x;
  const int per = (n + 1023) >> 10;
  const int start = tid * per;
  const int end = min(start + per, n);
  int s = 0;
  for (int i = start; i < end; ++i) s += cnt[i];
  part[tid] = s;
  __syncthreads();
  for (int off = 1; off < 1024; off <<= 1) {
    int v = (tid >= off) ? part[tid - off] : 0;
    __syncthreads();
    part[tid] += v;
    __syncthreads();
  }
  int run = (tid > 0) ? part[tid - 1] : 0;
  for (int i = start; i < end; ++i) {
    row_ptr[i] = run;
    int c = cnt[i];
    dinv[i] = rsqrtf((float)(c + 1));
    run += c;
  }
  if (tid == 1023) row_ptr[n] = part[1023];
}

__global__ void scatter_kernel(const int* __restrict__ src, const int* __restrict__ dst,
                               const int* __restrict__ rp, int* __restrict__ fill,
                               int* __restrict__ col, int E) {
  for (int e = blockIdx.x * blockDim.x + threadIdx.x; e < E; e += gridDim.x * blockDim.x) {
    int d = dst[e];
    int p = atomicAdd(&fill[d], 1);
    col[rp[d] + p] = src[e];
  }
}

// ------------------- GCN aggregation (gather, CSR by dst) -------------------
__launch_bounds__(256)
__global__ void gcn_agg(const float* __restrict__ h, const int* __restrict__ row_ptr,
                        const int* __restrict__ col, const float* __restrict__ dinv,
                        const float* __restrict__ bias, float* __restrict__ out,
                        int n, int F, int act) {
  const int tpn = F >> 2;
  const int npb = blockDim.x / tpn;
  const int node = blockIdx.x * npb + threadIdx.x / tpn;
  const int j = (threadIdx.x % tpn) << 2;
  if (node >= n) return;
  const float di = dinv[node];
  const float4 hv0 = *(const float4*)(h + (long)node * F + j);
  const float w0 = di * di;
  float ax = hv0.x * w0, ay = hv0.y * w0, az = hv0.z * w0, aw = hv0.w * w0;
  const int e0 = row_ptr[node], e1 = row_ptr[node + 1];
  for (int e = e0; e < e1; ++e) {
    const int s = col[e];
    const float w = dinv[s] * di;
    const float4 hv = *(const float4*)(h + (long)s * F + j);
    ax = fmaf(hv.x, w, ax);
    ay = fmaf(hv.y, w, ay);
    az = fmaf(hv.z, w, az);
    aw = fmaf(hv.w, w, aw);
  }
  const float4 bv = *(const float4*)(bias + j);
  float4 o;
  o.x = apply_act(ax + bv.x, act);
  o.y = apply_act(ay + bv.y, act);
  o.z = apply_act(az + bv.z, act);
  o.w = apply_act(aw + bv.w, act);
  *(float4*)(out + (long)node * F + j) = o;
}

// ----------------------------- misc small kernels ---------------------------
__global__ void reduce_part(const float* __restrict__ part, float* __restrict__ xt,
                            int n, int nsplit) {
  const int i = blockIdx.x * blockDim.x + threadIdx.x;
  if (i >= n) return;
  float s = 0.f;
  for (int sp = 0; sp < nsplit; ++sp) s += part[(long)sp * n + i];
  xt[i] = s;
}

__launch_bounds__(256)
__global__ void m1_kernel(const float* __restrict__ Wp, const float* __restrict__ bp,
                          const float* __restrict__ xg, float* __restrict__ M1b) {
  const int gid = blockIdx.x * blockDim.x + threadIdx.x;
  if (gid >= 513 * 128) return;
  const int m = gid >> 7, nn = gid & 127;
  const float* a = (m < 512) ? (Wp + (long)m * 3000) : bp;
  float acc = 0.f;
  for (int k = 0; k < 3000; k += 4) {
    acc = fmaf(a[k],     xg[(k)     * 128 + nn], acc);
    acc = fmaf(a[k + 1], xg[(k + 1) * 128 + nn], acc);
    acc = fmaf(a[k + 2], xg[(k + 2) * 128 + nn], acc);
    acc = fmaf(a[k + 3], xg[(k + 3) * 128 + nn], acc);
  }
  M1b[gid] = acc;
}

__launch_bounds__(256)
__global__ void l2norm_rows(const float* __restrict__ in, float* __restrict__ out, int F) {
  const int row = blockIdx.x;
  const float* r = in + (long)row * F;
  float s = 0.0f;
  for (int i = threadIdx.x * 4; i < F; i += blockDim.x * 4) {
    float4 v = *(const float4*)(r + i);
    s = fmaf(v.x, v.x, fmaf(v.y, v.y, fmaf(v.z, v.z, fmaf(v.w, v.w, s))));
  }
#pragma unroll
  for (int off = 32; off > 0; off >>= 1) s += __shfl_down(s, off);
  __shared__ float wsum[4];
  __shared__ float scale_s;
  const int wid = threadIdx.x >> 6;
  const int lane = threadIdx.x & 63;
  if (lane == 0) wsum[wid] = s;
  __syncthreads();
  if (threadIdx.x == 0) {
    float t = wsum[0] + wsum[1] + wsum[2] + wsum[3];
    scale_s = 1.0f / fmaxf(sqrtf(t), 1e-12f);
  }
  __syncthreads();
  const float sc = scale_s;
  float* o = out + (long)row * F;
  for (int i = threadIdx.x * 4; i < F; i += blockDim.x * 4) {
    float4 v = *(const float4*)(r + i);
    v.x *= sc; v.y *= sc; v.z *= sc; v.w *= sc;
    *(float4*)(o + i) = v;
  }
}

// ---------------------------------------------------------------------------
extern "C" void kernel_launch(void* const* d_in, const int* in_sizes, int n_in,
                              void* d_out, int out_size, void* d_ws, size_t ws_size,
                              hipStream_t stream) {
  const float* x0 = (const float*)d_in[0];
  const float* x1 = (const float*)d_in[1];
  const int*   ei  = (const int*)d_in[2];
  const int*   eig = (const int*)d_in[3];
  const float* Wm = (const float*)d_in[4];
  const float* bm = (const float*)d_in[5];
  const float* W1 = (const float*)d_in[6];
  const float* b1 = (const float*)d_in[7];
  const float* W2 = (const float*)d_in[8];
  const float* b2 = (const float*)d_in[9];
  const float* W3 = (const float*)d_in[10];
  const float* b3 = (const float*)d_in[11];
  const float* Wp = (const float*)d_in[12];
  const float* bp = (const float*)d_in[13];
  const float* Wg = (const float*)d_in[14];
  const float* bg = (const float*)d_in[15];

  // ---- workspace layout ----
  float* ws = (float*)d_ws;
  size_t o = 0;
  float* h1   = ws + o; o += (size_t)N_CELLS * HID;
  float* bufB = ws + o; o += (size_t)N_CELLS * HID;
  float* bufC = ws + o; o += (size_t)N_CELLS * HID;   // also: part (10 splits), zpre
  float* xt   = ws + o; o += (size_t)N_GENES * OUT;
  float* xg   = ws + o; o += (size_t)N_GENES * OUT;
  float* M1b  = ws + o; o += 513 * 128;
  float* dinv_c = ws + o; o += N_CELLS;
  float* dinv_g = ws + o; o += N_GENES + 64;
  int* ip = (int*)(ws + o);
  int* rp_c  = ip; ip += N_CELLS + 64;
  int* rp_g  = ip; ip += N_GENES + 64;
  int* col_c = ip; ip += E_CELL;
  int* col_g = ip; ip += E_GENE;
  int* cnt_c = ip; ip += N_CELLS;   // contiguous zero region starts here
  int* fill_c = ip; ip += N_CELLS;
  int* cnt_g = ip; ip += N_GENES;
  int* fill_g = ip; ip += N_GENES;
  unsigned short* us = (unsigned short*)(ip + N_GENES /* pad */);
  const int KP_G = 3072;  // padded K for N_GENES-K weights
  unsigned short* WmT = us; us += (size_t)HID * 2 * KP_G;
  unsigned short* W1T = us; us += (size_t)HID * 2 * KP_G;
  unsigned short* W2T = us; us += (size_t)HID * 2 * HID;
  unsigned short* W3T = us; us += (size_t)HID * 2 * HID;
  unsigned short* M1T = us; us += (size_t)OUT * 2 * HID;
  // aliases into bufC region (free at time of use)
  const int NSPLIT = 10;
  float* part = bufC;                               // step: gene TN gemm
  float* zpre = bufC + (size_t)NSPLIT * N_GENES * OUT;  // steps: z1/z2
  (void)ws_size; (void)in_sizes; (void)n_in; (void)out_size; (void)fill_g;

  const int* src_c = ei;  const int* dst_c = ei + E_CELL;
  const int* src_g = eig; const int* dst_g = eig + E_GENE;

  float* out_emb1 = (float*)d_out;
  float* out_emb2 = out_emb1 + (size_t)N_CELLS * HID;
  float* out_z1   = out_emb2 + (size_t)N_CELLS * HID;
  float* out_z2   = out_z1 + (size_t)N_CELLS * OUT;

  // ---- CSR build ----
  hipMemsetAsync(cnt_c, 0, (size_t)(2 * N_CELLS + 2 * N_GENES) * sizeof(int), stream);
  hist_kernel<<<1024, 256, 0, stream>>>(dst_c, cnt_c, E_CELL);
  hist_kernel<<<256, 256, 0, stream>>>(dst_g, cnt_g, E_GENE);
  scan_build<<<1, 1024, 0, stream>>>(cnt_c, rp_c, dinv_c, N_CELLS);
  scan_build<<<1, 1024, 0, stream>>>(cnt_g, rp_g, dinv_g, N_GENES);
  scatter_kernel<<<1024, 256, 0, stream>>>(src_c, dst_c, rp_c, fill_c, col_c, E_CELL);
  scatter_kernel<<<256, 256, 0, stream>>>(src_g, dst_g, rp_g, fill_g, col_g, E_GENE);

  // ---- weight conversions (transpose + bf16 hi/lo split + K-pad) ----
  conv_weight<<<dim3(HID / 32, KP_G / 32), 256, 0, stream>>>(Wm, WmT, N_GENES, HID, KP_G);
  conv_weight<<<dim3(HID / 32, KP_G / 32), 256, 0, stream>>>(W1, W1T, N_GENES, HID, KP_G);
  conv_weight<<<dim3(HID / 32, HID / 32), 256, 0, stream>>>(W2, W2T, HID, HID, HID);
  conv_weight<<<dim3(HID / 32, HID / 32), 256, 0, stream>>>(W3, W3T, HID, HID, HID);

  const dim3 gBig(HID / 128, (N_CELLS + 127) / 128);   // (4,157)
  const dim3 gOut(OUT / 128, (N_CELLS + 127) / 128);   // (1,157)

  // MLP branch: h1 = relu(x0 @ Wm + bm)
  gemm_mfma<<<gBig, 256, 0, stream>>>(x0, WmT, bm, h1, N_CELLS, HID, N_GENES, KP_G, ACT_RELU);

  // GCN branch
  gemm_mfma<<<gBig, 256, 0, stream>>>(x1, W1T, nullptr, bufB, N_CELLS, HID, N_GENES, KP_G, ACT_NONE);
  gcn_agg<<<N_CELLS / 2, 256, 0, stream>>>(bufB, rp_c, col_c, dinv_c, b1, bufC, N_CELLS, HID, ACT_LEAKY);
  gemm_mfma<<<gBig, 256, 0, stream>>>(bufC, W2T, nullptr, bufB, N_CELLS, HID, HID, HID, ACT_NONE);
  gcn_agg<<<N_CELLS / 2, 256, 0, stream>>>(bufB, rp_c, col_c, dinv_c, b2, bufC, N_CELLS, HID, ACT_LEAKY);
  gemm_mfma<<<gBig, 256, 0, stream>>>(bufC, W3T, b3, bufB, N_CELLS, HID, HID, HID, ACT_LEAKY);  // h2

  // gene branch (after W3 gemm so bufC region is free for part)
  const dim3 gtn((N_GENES + 127) / 128, NSPLIT);
  gemm_tn_splitk<<<gtn, 256, 0, stream>>>(x0, Wg, part, N_GENES, OUT, N_CELLS / NSPLIT);
  reduce_part<<<(N_GENES * OUT + 255) / 256, 256, 0, stream>>>(part, xt, N_GENES * OUT, NSPLIT);
  gcn_agg<<<(N_GENES + 7) / 8, 256, 0, stream>>>(xt, rp_g, col_g, dinv_g, bg, xg, N_GENES, OUT, ACT_RELU);

  // M1 = Wp @ xg (rows 0..511), bxg = bp @ xg (row 512); convert M1
  m1_kernel<<<(513 * 128 + 255) / 256, 256, 0, stream>>>(Wp, bp, xg, M1b);
  conv_weight<<<dim3(OUT / 32, HID / 32), 256, 0, stream>>>(M1b, M1T, HID, OUT, HID);
  const float* bxg = M1b + 512 * 128;

  // z1 = l2norm(h1 @ M1 + bxg); z2 = l2norm(h2 @ M1 + bxg)
  gemm_mfma<<<gOut, 256, 0, stream>>>(h1, M1T, bxg, zpre, N_CELLS, OUT, HID, HID, ACT_NONE);
  l2norm_rows<<<N_CELLS, 256, 0, stream>>>(zpre, out_z1, OUT);
  gemm_mfma<<<gOut, 256, 0, stream>>>(bufB, M1T, bxg, zpre, N_CELLS, OUT, HID, HID, ACT_NONE);
  l2norm_rows<<<N_CELLS, 256, 0, stream>>>(zpre, out_z2, OUT);

  // emb_1 / emb_2
  l2norm_rows<<<N_CELLS, 256, 0, stream>>>(h1, out_emb1, HID);
  l2norm_rows<<<N_CELLS, 256, 0, stream>>>(bufB, out_emb2, HID);
}